// Round 4
// baseline (511.389 us; speedup 1.0000x reference)
//
#include <hip/hip_runtime.h>

#define H 16
#define DK 64

typedef float vfloat4 __attribute__((ext_vector_type(4)));

// ---------------------------------------------------------------------------
// Kernel 1: per (b,h) precompute (unchanged — negligible runtime, verified)
// ---------------------------------------------------------------------------
__global__ __launch_bounds__(64) void prep_kernel(
    const float* __restrict__ R,
    const float* __restrict__ WQ_w, const float* __restrict__ WQ_b,
    const float* __restrict__ WK_w, const float* __restrict__ WK_b,
    const float* __restrict__ WV_w, const float* __restrict__ WV_b,
    float* __restrict__ u, float* __restrict__ rv, float* __restrict__ c) {
    const int bh = blockIdx.x;           // b*H + h
    const int e  = threadIdx.x;          // 0..63
    __shared__ float r_s[DK];
    __shared__ float rk_s[DK];

    r_s[e] = R[bh * DK + e];
    __syncthreads();

    float rk  = WK_b[e];
    float rvv = WV_b[e];
#pragma unroll
    for (int d = 0; d < DK; ++d) {
        rk  += r_s[d] * WK_w[e * DK + d];
        rvv += r_s[d] * WV_w[e * DK + d];
    }
    rk_s[e] = rk;
    rv[bh * DK + e] = rvv;
    __syncthreads();

    float uu = 0.f;
#pragma unroll
    for (int ee = 0; ee < DK; ++ee) uu += WQ_w[ee * DK + e] * rk_s[ee];
    u[bh * DK + e] = uu;

    if (e == 0) {
        float cc = 0.f;
        for (int ee = 0; ee < DK; ++ee) cc += WQ_b[ee] * rk_s[ee];
        c[bh] = cc;
    }
}

// ---------------------------------------------------------------------------
// Kernel 2: streaming pass — software-pipelined, mask-skipping.
//
// Block = 256 threads owns 64 consecutive rows of one batch, processed as
// 8 tiles x 8 rows with double-buffered register files (A/B). ISSUE(t+1)
// precedes COMPUTE(t) in a fully static schedule -> reads continuously in
// flight (the 431us baseline had read-issue duty cycle ~50%: load burst,
// then dead compute/store phase, then block exit).
//
// Masks are block-uniform: staged once into LDS, consumed via
// readfirstlane -> scalar s_cbranch around each row load. Skipped rows
// cost ZERO memory traffic (no dummy loads); consecutive uniform branches
// do not insert waitcnts, so live-row loads still pipeline back-to-back.
//
// Grid = dps * seq/64 = 1024 blocks = 4 blocks/CU at launch_bounds(256,4):
// one clean residency round, no launch churn.
// ---------------------------------------------------------------------------
#define TILE 8
#define TILES_PER_BLOCK 8
#define ROWS_PER_BLOCK (TILE * TILES_PER_BLOCK)   // 64

#define ISSUE(BUF, TL)                                                        \
    do {                                                                      \
        _Pragma("unroll")                                                     \
        for (int r = 0; r < TILE; ++r) {                                      \
            const int mm =                                                    \
                __builtin_amdgcn_readfirstlane(msh[(TL) * TILE + r]);         \
            if (mm)                                                           \
                BUF[r] = *(const vfloat4*)(sbase +                            \
                                           (size_t)((TL) * TILE + r) * 1024); \
            else                                                              \
                BUF[r] = (vfloat4)(0.f);                                      \
        }                                                                     \
    } while (0)

#define COMPUTE(BUF, TL)                                                      \
    do {                                                                      \
        _Pragma("unroll")                                                     \
        for (int r = 0; r < TILE; ++r) {                                      \
            const vfloat4 s4 = BUF[r];                                        \
            float p = s4.x * u4.x + s4.y * u4.y + s4.z * u4.z + s4.w * u4.w;  \
            p += __shfl_xor(p, 1);                                            \
            p += __shfl_xor(p, 2);                                            \
            p += __shfl_xor(p, 4);                                            \
            p += __shfl_xor(p, 8);                                            \
            const float beta = p + ch;                                        \
            const int mm = msh[(TL) * TILE + r];                              \
            vfloat4 o4;                                                       \
            o4.x = mm ? rv4.x * beta : 0.f;                                   \
            o4.y = mm ? rv4.y * beta : 0.f;                                   \
            o4.z = mm ? rv4.z * beta : 0.f;                                   \
            o4.w = mm ? rv4.w * beta : 0.f;                                   \
            __builtin_nontemporal_store(                                      \
                o4, (vfloat4*)(obase + (size_t)((TL) * TILE + r) * 1024));    \
        }                                                                     \
    } while (0)

__global__ __launch_bounds__(256, 4) void fused_kernel(
    const float* __restrict__ S, const int* __restrict__ S_mas,
    const float* __restrict__ u, const float* __restrict__ rv,
    const float* __restrict__ c, float* __restrict__ out,
    int seq_len, int blocks_per_batch) {
    const int t = threadIdx.x;
    const int b = blockIdx.x / blocks_per_batch;
    const int row0 = (blockIdx.x % blocks_per_batch) * ROWS_PER_BLOCK;
    const int d_model = H * DK;                    // 1024

    const int bh = b * H + (t >> 4);
    const vfloat4 u4  = *(const vfloat4*)(u  + bh * DK + (t & 15) * 4);
    const vfloat4 rv4 = *(const vfloat4*)(rv + bh * DK + (t & 15) * 4);
    const float   ch  = c[bh];

    const size_t base = (size_t)b * seq_len * d_model + (size_t)row0 * d_model + t * 4;
    const float* sbase = S + base;
    float*       obase = out + base;

    // Stage the block's 64 masks in LDS once (block-uniform values).
    __shared__ int msh[ROWS_PER_BLOCK];
    if (t < ROWS_PER_BLOCK) msh[t] = S_mas[(size_t)b * seq_len + row0 + t];
    __syncthreads();

    vfloat4 A[TILE], B[TILE];

    // Static double-buffered schedule: issue tile t+1, compute tile t.
    ISSUE(A, 0);
    ISSUE(B, 1); COMPUTE(A, 0);
    ISSUE(A, 2); COMPUTE(B, 1);
    ISSUE(B, 3); COMPUTE(A, 2);
    ISSUE(A, 4); COMPUTE(B, 3);
    ISSUE(B, 5); COMPUTE(A, 4);
    ISSUE(A, 6); COMPUTE(B, 5);
    ISSUE(B, 7); COMPUTE(A, 6);
    COMPUTE(B, 7);
}

extern "C" void kernel_launch(void* const* d_in, const int* in_sizes, int n_in,
                              void* d_out, int out_size, void* d_ws, size_t ws_size,
                              hipStream_t stream) {
    const float* S     = (const float*)d_in[0];
    const float* R     = (const float*)d_in[1];
    const int*   S_mas = (const int*)d_in[2];
    // d_in[3] = R_mas (dead in reference output)
    const float* WQ_w  = (const float*)d_in[4];
    const float* WQ_b  = (const float*)d_in[5];
    const float* WK_w  = (const float*)d_in[6];
    const float* WK_b  = (const float*)d_in[7];
    const float* WV_w  = (const float*)d_in[8];
    const float* WV_b  = (const float*)d_in[9];
    float* out = (float*)d_out;

    const int d_model = H * DK;                        // 1024
    const int dps     = in_sizes[1] / d_model;         // 32
    const int seq_len = in_sizes[0] / (dps * d_model); // 2048

    float* u_ws  = (float*)d_ws;                       // dps*H*DK floats
    float* rv_ws = u_ws + (size_t)dps * H * DK;        // dps*H*DK floats
    float* c_ws  = rv_ws + (size_t)dps * H * DK;       // dps*H floats

    prep_kernel<<<dps * H, 64, 0, stream>>>(R, WQ_w, WQ_b, WK_w, WK_b, WV_w, WV_b,
                                            u_ws, rv_ws, c_ws);

    const int blocks_per_batch = seq_len / ROWS_PER_BLOCK;   // 32
    fused_kernel<<<dps * blocks_per_batch, 256, 0, stream>>>(
        S, S_mas, u_ws, rv_ws, c_ws, out, seq_len, blocks_per_batch);
}

// Round 5
// 425.187 us; speedup vs baseline: 1.2027x; 1.2027x over previous
//
#include <hip/hip_runtime.h>

#define H 16
#define DK 64

typedef float vfloat4 __attribute__((ext_vector_type(4)));

// ---------------------------------------------------------------------------
// Kernel 1: per (b,h) precompute (unchanged — negligible runtime, verified)
//   R_K[e] = sum_d R[b,h,d]*WK_w[e,d] + WK_b[e]
//   R_V[e] = sum_d R[b,h,d]*WV_w[e,d] + WV_b[e]
//   u[d]   = sum_e WQ_w[e,d]*R_K[e]           (WQ folded into the gate)
//   c      = sum_e WQ_b[e]*R_K[e]
// ---------------------------------------------------------------------------
__global__ __launch_bounds__(64) void prep_kernel(
    const float* __restrict__ R,
    const float* __restrict__ WQ_w, const float* __restrict__ WQ_b,
    const float* __restrict__ WK_w, const float* __restrict__ WK_b,
    const float* __restrict__ WV_w, const float* __restrict__ WV_b,
    float* __restrict__ u, float* __restrict__ rv, float* __restrict__ c) {
    const int bh = blockIdx.x;           // b*H + h
    const int e  = threadIdx.x;          // 0..63
    __shared__ float r_s[DK];
    __shared__ float rk_s[DK];

    r_s[e] = R[bh * DK + e];             // R is (dps,1,H*DK) contiguous
    __syncthreads();

    float rk  = WK_b[e];
    float rvv = WV_b[e];
#pragma unroll
    for (int d = 0; d < DK; ++d) {
        rk  += r_s[d] * WK_w[e * DK + d];
        rvv += r_s[d] * WV_w[e * DK + d];
    }
    rk_s[e] = rk;
    rv[bh * DK + e] = rvv;
    __syncthreads();

    float uu = 0.f;
#pragma unroll
    for (int ee = 0; ee < DK; ++ee) uu += WQ_w[ee * DK + e] * rk_s[ee];
    u[bh * DK + e] = uu;

    if (e == 0) {
        float cc = 0.f;
        for (int ee = 0; ee < DK; ++ee) cc += WQ_b[ee] * rk_s[ee];
        c[bh] = cc;
    }
}

// ---------------------------------------------------------------------------
// Kernel 2: streaming pass over S — branchless MLP=16, REGULAR stores.
//
// Round-4 counter evidence:
//   - __builtin_nontemporal_store caused 2.18x write amplification
//     (WRITE_SIZE 585 MB vs 268 MB logical: nt bypasses L2 merge -> partial
//     128B lines stream out twice + DRAM read-modify-write). The harness's
//     fillBufferAligned writes exactly 1.00x with regular stores at 6.5 TB/s.
//     => stores are now plain; L2 merges them into full lines.
//   - Occupancy is irrelevant for streaming BW (fills: 81% peak at 9.9%
//     occupancy), so no launch_bounds min-wave tuning.
//
// Structure = round-1 measured-fast version: all 16 row-loads issue
// unconditionally (address-select redirects masked rows to the block's row 0
// -> coalesced, L2-resident, ~16 MB total extra); result select replaces the
// branch, so loads pipeline back-to-back with one waitcnt.
// ---------------------------------------------------------------------------
#define ROWS_PER_BLOCK 16

__global__ __launch_bounds__(256) void fused_kernel(
    const float* __restrict__ S, const int* __restrict__ S_mas,
    const float* __restrict__ u, const float* __restrict__ rv,
    const float* __restrict__ c, float* __restrict__ out,
    int seq_len, int blocks_per_batch) {
    const int t = threadIdx.x;
    const int h = t >> 4;                          // head 0..15
    const int b = blockIdx.x / blocks_per_batch;
    const int srow0 = (blockIdx.x % blocks_per_batch) * ROWS_PER_BLOCK;
    const int d_model = H * DK;                    // 1024

    const int bh = b * H + h;
    const vfloat4 u4  = *(const vfloat4*)(u  + bh * DK + (t & 15) * 4);
    const vfloat4 rv4 = *(const vfloat4*)(rv + bh * DK + (t & 15) * 4);
    const float   ch  = c[bh];

    const size_t base = (size_t)b * seq_len * d_model + (size_t)srow0 * d_model + t * 4;
    const float* srow = S + base;
    float*       orow = out + base;
    const int*   mrow = S_mas + (size_t)b * seq_len + srow0;

    // Hoist all mask loads (latency overlaps).
    int m[ROWS_PER_BLOCK];
#pragma unroll
    for (int r = 0; r < ROWS_PER_BLOCK; ++r) m[r] = mrow[r];

    // Issue ALL row loads unconditionally. Masked rows read the block's
    // row 0 instead (address select, no control flow) -> 16 loads in
    // flight per wave, one waitcnt covers them all.
    vfloat4 sdat[ROWS_PER_BLOCK];
#pragma unroll
    for (int r = 0; r < ROWS_PER_BLOCK; ++r) {
        const size_t off = (m[r] != 0) ? (size_t)r * d_model : 0;
        sdat[r] = *(const vfloat4*)(srow + off);
    }

#pragma unroll
    for (int r = 0; r < ROWS_PER_BLOCK; ++r) {
        const vfloat4 s4 = sdat[r];
        float p = s4.x * u4.x + s4.y * u4.y + s4.z * u4.z + s4.w * u4.w;
        p += __shfl_xor(p, 1);
        p += __shfl_xor(p, 2);
        p += __shfl_xor(p, 4);
        p += __shfl_xor(p, 8);
        const float beta = p + ch;
        const bool live = (m[r] != 0);
        vfloat4 o4;
        o4.x = live ? rv4.x * beta : 0.f;
        o4.y = live ? rv4.y * beta : 0.f;
        o4.z = live ? rv4.z * beta : 0.f;
        o4.w = live ? rv4.w * beta : 0.f;
        *(vfloat4*)(orow + (size_t)r * d_model) = o4;   // regular store: L2 merges full lines
    }
}

extern "C" void kernel_launch(void* const* d_in, const int* in_sizes, int n_in,
                              void* d_out, int out_size, void* d_ws, size_t ws_size,
                              hipStream_t stream) {
    const float* S     = (const float*)d_in[0];
    const float* R     = (const float*)d_in[1];
    const int*   S_mas = (const int*)d_in[2];
    // d_in[3] = R_mas (dead in reference output)
    const float* WQ_w  = (const float*)d_in[4];
    const float* WQ_b  = (const float*)d_in[5];
    const float* WK_w  = (const float*)d_in[6];
    const float* WK_b  = (const float*)d_in[7];
    const float* WV_w  = (const float*)d_in[8];
    const float* WV_b  = (const float*)d_in[9];
    float* out = (float*)d_out;

    const int d_model = H * DK;                        // 1024
    const int dps     = in_sizes[1] / d_model;         // 32
    const int seq_len = in_sizes[0] / (dps * d_model); // 2048

    float* u_ws  = (float*)d_ws;                       // dps*H*DK floats
    float* rv_ws = u_ws + (size_t)dps * H * DK;        // dps*H*DK floats
    float* c_ws  = rv_ws + (size_t)dps * H * DK;       // dps*H floats

    prep_kernel<<<dps * H, 64, 0, stream>>>(R, WQ_w, WQ_b, WK_w, WK_b, WV_w, WV_b,
                                            u_ws, rv_ws, c_ws);

    const int blocks_per_batch = seq_len / ROWS_PER_BLOCK;   // 128
    fused_kernel<<<dps * blocks_per_batch, 256, 0, stream>>>(
        S, S_mas, u_ws, rv_ws, c_ws, out, seq_len, blocks_per_batch);
}